// Round 1
// baseline (108.099 us; speedup 1.0000x reference)
//
#include <hip/hip_runtime.h>
#include <math.h>

#define N 8192
#define IN_F 256
#define HID 256
#define ALPHA 0.2f

// ---------------------------------------------------------------------------
// Kernel A: wa1[m] = sum_k W[m][k]*a1[k], wa2[m] = sum_k W[m][k]*a2[k]
// grid = 256 blocks (one per m), 64 threads (one wave), coalesced float4 row read.
// ---------------------------------------------------------------------------
__global__ void compute_wa(const float* __restrict__ W, const float* __restrict__ a,
                           float* __restrict__ wa /* [512]: wa1 | wa2 */) {
    const int m = blockIdx.x;
    const int lane = threadIdx.x;                 // 0..63
    const float4 w  = ((const float4*)(W + m * HID))[lane];
    const float4 a1 = ((const float4*)(a))[lane];
    const float4 a2 = ((const float4*)(a + HID))[lane];
    float s1 = w.x * a1.x + w.y * a1.y + w.z * a1.z + w.w * a1.w;
    float s2 = w.x * a2.x + w.y * a2.y + w.z * a2.z + w.w * a2.w;
#pragma unroll
    for (int off = 32; off > 0; off >>= 1) {
        s1 += __shfl_xor(s1, off);
        s2 += __shfl_xor(s2, off);
    }
    if (lane == 0) {
        wa[m]       = s1;
        wa[HID + m] = s2;
    }
}

// ---------------------------------------------------------------------------
// Kernel B: f1[i] = src[i,:] . wa1, f2[i] = src[i,:] . wa2
// One wave per row; 4 rows per 256-thread block; 2048 blocks.
// ---------------------------------------------------------------------------
__global__ void compute_f(const float* __restrict__ src, const float* __restrict__ wa,
                          float* __restrict__ f1, float* __restrict__ f2) {
    const int wave = threadIdx.x >> 6;
    const int lane = threadIdx.x & 63;
    const int row  = blockIdx.x * 4 + wave;
    const float4 v  = ((const float4*)(src + (size_t)row * IN_F))[lane];
    const float4 x1 = ((const float4*)(wa))[lane];
    const float4 x2 = ((const float4*)(wa + HID))[lane];
    float s1 = v.x * x1.x + v.y * x1.y + v.z * x1.z + v.w * x1.w;
    float s2 = v.x * x2.x + v.y * x2.y + v.z * x2.z + v.w * x2.w;
#pragma unroll
    for (int off = 32; off > 0; off >>= 1) {
        s1 += __shfl_xor(s1, off);
        s2 += __shfl_xor(s2, off);
    }
    if (lane == 0) {
        f1[row] = s1;
        f2[row] = s2;
    }
}

// ---------------------------------------------------------------------------
// Kernel C: one block per row. e = leaky(f1[row] + f2[col]) + bias[row][col],
// row-softmax, write out. Row (8192 f32) lives entirely in registers:
// 256 threads x 32 values. bias read ONCE, out written ONCE.
// Thread t handles float4 columns {t + 256*u : u=0..7} -> fully coalesced.
// ---------------------------------------------------------------------------
__global__ __launch_bounds__(256) void attn_softmax(
    const float* __restrict__ bias, const float* __restrict__ f1,
    const float* __restrict__ f2, float* __restrict__ out) {
    const int row = blockIdx.x;
    const int t   = threadIdx.x;
    const float f1i = f1[row];

    const float4* __restrict__ brow = (const float4*)(bias + (size_t)row * N);
    const float4* __restrict__ f2v  = (const float4*)f2;
    float4* __restrict__ orow       = (float4*)(out + (size_t)row * N);

    float e[32];
    float lmax = -3.4e38f;
#pragma unroll
    for (int u = 0; u < 8; ++u) {
        const int idx = u * 256 + t;
        const float4 b = brow[idx];
        const float4 g = f2v[idx];
        float4 v;
        v.x = f1i + g.x; v.y = f1i + g.y; v.z = f1i + g.z; v.w = f1i + g.w;
        v.x = (v.x > 0.f ? v.x : ALPHA * v.x) + b.x;
        v.y = (v.y > 0.f ? v.y : ALPHA * v.y) + b.y;
        v.z = (v.z > 0.f ? v.z : ALPHA * v.z) + b.z;
        v.w = (v.w > 0.f ? v.w : ALPHA * v.w) + b.w;
        e[u * 4 + 0] = v.x; e[u * 4 + 1] = v.y;
        e[u * 4 + 2] = v.z; e[u * 4 + 3] = v.w;
        lmax = fmaxf(lmax, fmaxf(fmaxf(v.x, v.y), fmaxf(v.z, v.w)));
    }

    __shared__ float smax[4];
    __shared__ float ssum[4];
    const int wave = t >> 6, lane = t & 63;

    // block-wide max
#pragma unroll
    for (int off = 32; off > 0; off >>= 1) lmax = fmaxf(lmax, __shfl_xor(lmax, off));
    if (lane == 0) smax[wave] = lmax;
    __syncthreads();
    const float gmax = fmaxf(fmaxf(smax[0], smax[1]), fmaxf(smax[2], smax[3]));

    // exp + block-wide sum
    float lsum = 0.f;
#pragma unroll
    for (int i = 0; i < 32; ++i) {
        e[i] = __expf(e[i] - gmax);
        lsum += e[i];
    }
#pragma unroll
    for (int off = 32; off > 0; off >>= 1) lsum += __shfl_xor(lsum, off);
    if (lane == 0) ssum[wave] = lsum;
    __syncthreads();
    const float inv = 1.f / (ssum[0] + ssum[1] + ssum[2] + ssum[3]);

#pragma unroll
    for (int u = 0; u < 8; ++u) {
        const int idx = u * 256 + t;
        float4 v;
        v.x = e[u * 4 + 0] * inv; v.y = e[u * 4 + 1] * inv;
        v.z = e[u * 4 + 2] * inv; v.w = e[u * 4 + 3] * inv;
        orow[idx] = v;
    }
}

extern "C" void kernel_launch(void* const* d_in, const int* in_sizes, int n_in,
                              void* d_out, int out_size, void* d_ws, size_t ws_size,
                              hipStream_t stream) {
    const float* src  = (const float*)d_in[0];   // (8192, 256)
    const float* bias = (const float*)d_in[1];   // (8192, 8192)
    const float* W    = (const float*)d_in[2];   // (256, 256)
    const float* a    = (const float*)d_in[3];   // (512, 1)
    float* out = (float*)d_out;

    // workspace layout (floats): wa[0:512), f1[512:8704), f2[8704:16896)
    float* ws = (float*)d_ws;
    float* wa = ws;
    float* f1 = ws + 512;
    float* f2 = ws + 512 + N;

    compute_wa<<<HID, 64, 0, stream>>>(W, a, wa);
    compute_f<<<N / 4, 256, 0, stream>>>(src, wa, f1, f2);
    attn_softmax<<<N, 256, 0, stream>>>(bias, f1, f2, out);
}

// Round 2
// 99.685 us; speedup vs baseline: 1.0844x; 1.0844x over previous
//
#include <hip/hip_runtime.h>
#include <math.h>

#define N 8192
#define IN_F 256
#define HID 256
#define ALPHA 0.2f

typedef float f32x4 __attribute__((ext_vector_type(4)));

// ---------------------------------------------------------------------------
// Kernel A: wa1[m] = sum_k W[m][k]*a1[k], wa2[m] = sum_k W[m][k]*a2[k]
// ---------------------------------------------------------------------------
__global__ void compute_wa(const float* __restrict__ W, const float* __restrict__ a,
                           float* __restrict__ wa /* [512]: wa1 | wa2 */) {
    const int m = blockIdx.x;
    const int lane = threadIdx.x;                 // 0..63
    const float4 w  = ((const float4*)(W + m * HID))[lane];
    const float4 a1 = ((const float4*)(a))[lane];
    const float4 a2 = ((const float4*)(a + HID))[lane];
    float s1 = w.x * a1.x + w.y * a1.y + w.z * a1.z + w.w * a1.w;
    float s2 = w.x * a2.x + w.y * a2.y + w.z * a2.z + w.w * a2.w;
#pragma unroll
    for (int off = 32; off > 0; off >>= 1) {
        s1 += __shfl_xor(s1, off);
        s2 += __shfl_xor(s2, off);
    }
    if (lane == 0) {
        wa[m]       = s1;
        wa[HID + m] = s2;
    }
}

// ---------------------------------------------------------------------------
// Kernel B: f1[i] = src[i,:] . wa1, f2[i] = src[i,:] . wa2
// One wave per row; 4 rows per 256-thread block.
// ---------------------------------------------------------------------------
__global__ void compute_f(const float* __restrict__ src, const float* __restrict__ wa,
                          float* __restrict__ f1, float* __restrict__ f2) {
    const int wave = threadIdx.x >> 6;
    const int lane = threadIdx.x & 63;
    const int row  = blockIdx.x * 4 + wave;
    const float4 v  = ((const float4*)(src + (size_t)row * IN_F))[lane];
    const float4 x1 = ((const float4*)(wa))[lane];
    const float4 x2 = ((const float4*)(wa + HID))[lane];
    float s1 = v.x * x1.x + v.y * x1.y + v.z * x1.z + v.w * x1.w;
    float s2 = v.x * x2.x + v.y * x2.y + v.z * x2.z + v.w * x2.w;
#pragma unroll
    for (int off = 32; off > 0; off >>= 1) {
        s1 += __shfl_xor(s1, off);
        s2 += __shfl_xor(s2, off);
    }
    if (lane == 0) {
        f1[row] = s1;
        f2[row] = s2;
    }
}

// ---------------------------------------------------------------------------
// Kernel C: one block (512 threads) per row.
//   e = leaky(f1[row] + f2[col]) + bias[row][col]; row-softmax; store.
// Single-barrier softmax: per-wave max m_w and per-wave sum
//   s_w = sum(exp(e - m_w)); combine across 8 waves after ONE __syncthreads:
//   M = max m_w, S = sum s_w * exp(m_w - M); out = exp(e - m_w) * exp(m_w-M)/S
//   = exp(e - M)/S  (exact same math as two-pass).
// bias loads + out stores are nontemporal (touch-once, keep out of L2);
// f2 stays cached (reused by every block).
// ---------------------------------------------------------------------------
__global__ __launch_bounds__(512) void attn_softmax(
    const float* __restrict__ bias, const float* __restrict__ f1,
    const float* __restrict__ f2, float* __restrict__ out) {
    const int row = blockIdx.x;
    const int t   = threadIdx.x;          // 0..511
    const float f1i = f1[row];

    const f32x4* __restrict__ brow = (const f32x4*)(bias + (size_t)row * N);
    const f32x4* __restrict__ f2v  = (const f32x4*)f2;
    f32x4* __restrict__ orow       = (f32x4*)(out + (size_t)row * N);

    float e[16];
    float lmax = -3.4e38f;
#pragma unroll
    for (int u = 0; u < 4; ++u) {
        const int idx = u * 512 + t;
        const f32x4 b = __builtin_nontemporal_load(&brow[idx]);
        const f32x4 g = f2v[idx];
        f32x4 v = f1i + g;
        v.x = (v.x > 0.f ? v.x : ALPHA * v.x) + b.x;
        v.y = (v.y > 0.f ? v.y : ALPHA * v.y) + b.y;
        v.z = (v.z > 0.f ? v.z : ALPHA * v.z) + b.z;
        v.w = (v.w > 0.f ? v.w : ALPHA * v.w) + b.w;
        e[u * 4 + 0] = v.x; e[u * 4 + 1] = v.y;
        e[u * 4 + 2] = v.z; e[u * 4 + 3] = v.w;
        lmax = fmaxf(lmax, fmaxf(fmaxf(v.x, v.y), fmaxf(v.z, v.w)));
    }

    // per-wave max
#pragma unroll
    for (int off = 32; off > 0; off >>= 1) lmax = fmaxf(lmax, __shfl_xor(lmax, off));

    // exp relative to wave max + per-wave sum
    float lsum = 0.f;
#pragma unroll
    for (int i = 0; i < 16; ++i) {
        e[i] = __expf(e[i] - lmax);
        lsum += e[i];
    }
#pragma unroll
    for (int off = 32; off > 0; off >>= 1) lsum += __shfl_xor(lsum, off);

    __shared__ float wm[8];
    __shared__ float wsum[8];
    const int wave = t >> 6, lane = t & 63;
    if (lane == 0) { wm[wave] = lmax; wsum[wave] = lsum; }
    __syncthreads();                       // the ONLY barrier

    float M = wm[0];
#pragma unroll
    for (int w = 1; w < 8; ++w) M = fmaxf(M, wm[w]);
    float S = 0.f;
#pragma unroll
    for (int w = 0; w < 8; ++w) S += wsum[w] * __expf(wm[w] - M);
    const float scale = __expf(lmax - M) / S;   // per-wave correction / denom

#pragma unroll
    for (int u = 0; u < 4; ++u) {
        const int idx = u * 512 + t;
        f32x4 v;
        v.x = e[u * 4 + 0] * scale; v.y = e[u * 4 + 1] * scale;
        v.z = e[u * 4 + 2] * scale; v.w = e[u * 4 + 3] * scale;
        __builtin_nontemporal_store(v, &orow[idx]);
    }
}

extern "C" void kernel_launch(void* const* d_in, const int* in_sizes, int n_in,
                              void* d_out, int out_size, void* d_ws, size_t ws_size,
                              hipStream_t stream) {
    const float* src  = (const float*)d_in[0];   // (8192, 256)
    const float* bias = (const float*)d_in[1];   // (8192, 8192)
    const float* W    = (const float*)d_in[2];   // (256, 256)
    const float* a    = (const float*)d_in[3];   // (512, 1)
    float* out = (float*)d_out;

    // workspace layout (floats): wa[0:512), f1[512:8704), f2[8704:16896)
    float* ws = (float*)d_ws;
    float* wa = ws;
    float* f1 = ws + 512;
    float* f2 = ws + 512 + N;

    compute_wa<<<HID, 64, 0, stream>>>(W, a, wa);
    compute_f<<<N / 4, 256, 0, stream>>>(src, wa, f1, f2);
    attn_softmax<<<N, 512, 0, stream>>>(bias, f1, f2, out);
}